// Round 4
// baseline (657.313 us; speedup 1.0000x reference)
//
#include <hip/hip_runtime.h>
#include <hip/hip_bf16.h>

typedef unsigned int uint;
typedef unsigned short ushort;

constexpr int Bn = 256, Sn = 512, Vn = 32000, Dn = 100, Hn = 75, Ln = 128;
constexpr int EW = 80;    // embW row stride (floats) — covers j-pad reads 75..79
constexpr int KP = 96;    // padded K for MFMA (3 x 32)
constexpr int LSTR = 104; // LDS h/o row stride in ushorts (bank-conflict-free)

// workspace layout (float units)
constexpr size_t OFF_EMBW = 0;                        // Vn*EW = 2,560,000 f
constexpr size_t OFF_W2H  = OFF_EMBW + (size_t)Vn*EW; // 80*96 ush = 3840 f each
constexpr size_t OFF_W2L  = OFF_W2H + 3840;
constexpr size_t OFF_WOH  = OFF_W2L + 3840;
constexpr size_t OFF_WOL  = OFF_WOH + 3840;
constexpr size_t OFF_WFH  = OFF_WOL + 3840;           // 128*96 ush = 6144 f
constexpr size_t OFF_WFL  = OFF_WFH + 6144;

typedef __attribute__((ext_vector_type(8))) short short8;   // 8 bf16
typedef __attribute__((ext_vector_type(4))) float floatx4;  // MFMA C/D

__device__ __forceinline__ float bf2f(ushort u){ return __uint_as_float(((uint)u) << 16); }
__device__ __forceinline__ ushort f2bf(float f){
    union { __hip_bfloat16 h; ushort u; } v; v.h = __float2bfloat16(f); return v.u;
}
__device__ __forceinline__ float sigmoidf(float z){ return 1.f/(1.f + __expf(-z)); }
// barrier with LDS-only drain: global prefetch/stores stay in flight
__device__ __forceinline__ void bar_lds(){ asm volatile("s_waitcnt lgkmcnt(0)\ns_barrier" ::: "memory"); }

// ---------------------------------------------------------------------------
// Weight prep: W2,Wo -> 80x96 bf16 hi+lo (rows/cols >=75 zero); Wfc -> 128x96
// ---------------------------------------------------------------------------
__global__ __launch_bounds__(256) void k_wprep(
    const float* __restrict__ W2, const float* __restrict__ Wo,
    const float* __restrict__ Wfc, ushort* __restrict__ w2h, ushort* __restrict__ w2l,
    ushort* __restrict__ woh, ushort* __restrict__ wol,
    ushort* __restrict__ wfh, ushort* __restrict__ wfl)
{
    const int tid = blockIdx.x*256 + threadIdx.x;
    const int stride = gridDim.x*256;
    for (int i = tid; i < 80*KP; i += stride){
        int nidx = i / KP, k = i % KP;
        bool ok = (nidx < Hn && k < Hn);
        float v2 = ok ? W2[nidx*Hn + k] : 0.f;
        float vo = ok ? Wo[nidx*Hn + k] : 0.f;
        ushort h2 = f2bf(v2), ho = f2bf(vo);
        w2h[i] = h2; w2l[i] = f2bf(v2 - bf2f(h2));
        woh[i] = ho; wol[i] = f2bf(vo - bf2f(ho));
    }
    for (int i = tid; i < Ln*KP; i += stride){
        int l = i / KP, k = i % KP;
        float v = (k < Hn) ? Wfc[l*Hn + k] : 0.f;
        ushort h = f2bf(v);
        wfh[i] = h; wfl[i] = f2bf(v - bf2f(h));
    }
}

// ---------------------------------------------------------------------------
// embW[v][j] = sum_d emb[v][d]*W1[j][d] + b1[j] + b2[j], stride EW=80,
// cols 75..79 zeroed (safe xp-pad reads). One wave per 64 vocab rows.
// ---------------------------------------------------------------------------
__global__ __launch_bounds__(64) void k_embproj(
    const float* __restrict__ emb, const float* __restrict__ W1,
    const float* __restrict__ b1, const float* __restrict__ b2,
    float* __restrict__ embW)
{
    const int lane = threadIdx.x;
    const int v = blockIdx.x*64 + lane;
    const float4* ev = (const float4*)(emb + (size_t)v*Dn);
    float e[Dn];
    #pragma unroll
    for (int q = 0; q < Dn/4; ++q){
        float4 x = ev[q];
        e[4*q] = x.x; e[4*q+1] = x.y; e[4*q+2] = x.z; e[4*q+3] = x.w;
    }
    __shared__ float s_out[64*EW];
    #pragma unroll 4
    for (int j = 0; j < Hn; ++j){
        float a0 = b1[j] + b2[j], a1 = 0.f, a2 = 0.f, a3 = 0.f;
        const float* w = W1 + j*Dn;              // uniform -> s_loads
        #pragma unroll
        for (int d = 0; d < Dn; d += 4){
            a0 += w[d]*e[d];     a1 += w[d+1]*e[d+1];
            a2 += w[d+2]*e[d+2]; a3 += w[d+3]*e[d+3];
        }
        s_out[lane*EW + j] = (a0+a1) + (a2+a3);
    }
    #pragma unroll
    for (int j = Hn; j < EW; ++j) s_out[lane*EW + j] = 0.f;
    __syncthreads();
    float* dst = embW + (size_t)blockIdx.x*64*EW;
    for (int i = lane; i < 64*EW; i += 64) dst[i] = s_out[i];
}

// ---------------------------------------------------------------------------
// Fused RNN scan + output head. One block = 16 batch rows, 5 waves, 514 iters.
// z^T formulation: A = weight tiles (regs), B = h/o in LDS [row][k] (LSTR=104).
//   iter i: z-phase  (i<Sn):      h_i = sigma(W2@h_{i-1} + xp_i)     (all waves)
//           o-phase  (1<=i<=Sn):  o_{i-1} = sigma(Wo@h_{i-1} + bo)   (waves 0-2)
//           out-ph   (i>=2):      out_{i-2} = Wfc@o_{i-2} + bfc      (waves 3,4)
// o reuses z's h B-frags (no extra LDS reads). One lgkm-only barrier per iter.
// C->B transform: C rows = 4 consecutive j for one batchrow -> ds_write_b64;
// next B-frag = ds_read_b128. xp: dwordx4 gather prefetched 2 iters ahead.
// ---------------------------------------------------------------------------
__global__ __launch_bounds__(320) void k_rnn_fused(
    const int* __restrict__ X, const float* __restrict__ embW,
    const ushort* __restrict__ w2h, const ushort* __restrict__ w2l,
    const ushort* __restrict__ woh, const ushort* __restrict__ wol,
    const ushort* __restrict__ wfh, const ushort* __restrict__ wfl,
    const float* __restrict__ bo, const float* __restrict__ bfc,
    float* __restrict__ out)
{
    const int tid  = threadIdx.x;
    const int w    = tid >> 6;       // wave 0..4 = z-tile id
    const int lane = tid & 63;
    const int n    = lane & 15;      // batchrow-within-block (B n-dim / A m-dim)
    const int g    = lane >> 4;      // k-group
    const int b0   = blockIdx.x * 16;
    const int j0   = 16*w + 4*g;     // this lane's z output rows (j0..j0+3)

    __shared__ int    sX[16*513];                 // +1 pad: conflict-free
    __shared__ __align__(16) ushort hbuf[2][16*LSTR];
    __shared__ __align__(16) ushort obuf[2][16*LSTR];

    for (int idx = tid; idx < 16*Sn; idx += 320){
        int row = idx >> 9, ii = idx & 511;
        sX[row*513 + ii] = X[(size_t)(b0 + row)*Sn + ii];
    }
    for (int idx = tid; idx < 16*LSTR; idx += 320){
        hbuf[0][idx] = 0; hbuf[1][idx] = 0;       // h_{-1}=0 + pads
        obuf[0][idx] = 0; obuf[1][idx] = 0;
    }
    // W2 A-frags (all waves)
    short8 a2h[3], a2l[3];
    #pragma unroll
    for (int ks = 0; ks < 3; ++ks){
        a2h[ks] = *(const short8*)(w2h + (16*w + n)*KP + ks*32 + g*8);
        a2l[ks] = *(const short8*)(w2l + (16*w + n)*KP + ks*32 + g*8);
    }
    __syncthreads();

    // xp prefetch pipeline (2 deep)
    float4 xp_cur, xp_nxt;
    {
        int t0 = sX[n*513 + 0], t1 = sX[n*513 + 1];
        xp_cur = *(const float4*)(embW + (size_t)t0*EW + j0);
        xp_nxt = *(const float4*)(embW + (size_t)t1*EW + j0);
    }

    if (w < 3){
        // ---- role A: z + o-phase.  o-tiles: w0:{0,1} w1:{2,3} w2:{4} ----
        const int t0 = 2*w, t1 = (w < 2) ? 2*w+1 : 4;
        short8 aoh0[3], aol0[3], aoh1[3], aol1[3];
        float bo0[4], bo1[4];
        #pragma unroll
        for (int ks = 0; ks < 3; ++ks){
            aoh0[ks] = *(const short8*)(woh + (16*t0 + n)*KP + ks*32 + g*8);
            aol0[ks] = *(const short8*)(wol + (16*t0 + n)*KP + ks*32 + g*8);
            aoh1[ks] = *(const short8*)(woh + (16*t1 + n)*KP + ks*32 + g*8);
            aol1[ks] = *(const short8*)(wol + (16*t1 + n)*KP + ks*32 + g*8);
        }
        #pragma unroll
        for (int r = 0; r < 4; ++r){
            int i0 = 16*t0 + 4*g + r, i1 = 16*t1 + 4*g + r;
            bo0[r] = (i0 < Hn) ? bo[i0] : 0.f;
            bo1[r] = (i1 < Hn) ? bo[i1] : 0.f;
        }
        for (int i = 0; i < Sn+2; ++i){
            const int cur = i & 1, nxt = cur ^ 1;
            short8 hb0, hb1, hb2;
            if (i <= Sn){
                const ushort* hp = hbuf[cur] + n*LSTR + g*8;
                hb0 = *(const short8*)hp;
                hb1 = *(const short8*)(hp + 32);
                hb2 = *(const short8*)(hp + 64);
            }
            // issue xp prefetch early (consumed at iter i+2)
            float4 xp_new = {0.f,0.f,0.f,0.f};
            if (i + 2 < Sn){
                int tok = sX[n*513 + i + 2];
                xp_new = *(const float4*)(embW + (size_t)tok*EW + j0);
            }
            if (i < Sn){ // z-phase -> h_i
                floatx4 zh = {0.f,0.f,0.f,0.f}, zl = {0.f,0.f,0.f,0.f};
                zh = __builtin_amdgcn_mfma_f32_16x16x32_bf16(a2h[0], hb0, zh, 0,0,0);
                zh = __builtin_amdgcn_mfma_f32_16x16x32_bf16(a2h[1], hb1, zh, 0,0,0);
                zh = __builtin_amdgcn_mfma_f32_16x16x32_bf16(a2h[2], hb2, zh, 0,0,0);
                zl = __builtin_amdgcn_mfma_f32_16x16x32_bf16(a2l[0], hb0, zl, 0,0,0);
                zl = __builtin_amdgcn_mfma_f32_16x16x32_bf16(a2l[1], hb1, zl, 0,0,0);
                zl = __builtin_amdgcn_mfma_f32_16x16x32_bf16(a2l[2], hb2, zl, 0,0,0);
                uint u0 = f2bf(sigmoidf(zh[0]+zl[0]+xp_cur.x));
                uint u1 = f2bf(sigmoidf(zh[1]+zl[1]+xp_cur.y));
                uint u2 = f2bf(sigmoidf(zh[2]+zl[2]+xp_cur.z));
                uint u3 = f2bf(sigmoidf(zh[3]+zl[3]+xp_cur.w));
                uint2 pk; pk.x = u0 | (u1<<16); pk.y = u2 | (u3<<16);
                *(uint2*)(hbuf[nxt] + n*LSTR + j0) = pk;
            }
            if (i >= 1 && i <= Sn){ // o-phase -> o_{i-1} (reuses hb frags)
                floatx4 oh = {0.f,0.f,0.f,0.f}, ol = {0.f,0.f,0.f,0.f};
                oh = __builtin_amdgcn_mfma_f32_16x16x32_bf16(aoh0[0], hb0, oh, 0,0,0);
                oh = __builtin_amdgcn_mfma_f32_16x16x32_bf16(aoh0[1], hb1, oh, 0,0,0);
                oh = __builtin_amdgcn_mfma_f32_16x16x32_bf16(aoh0[2], hb2, oh, 0,0,0);
                ol = __builtin_amdgcn_mfma_f32_16x16x32_bf16(aol0[0], hb0, ol, 0,0,0);
                ol = __builtin_amdgcn_mfma_f32_16x16x32_bf16(aol0[1], hb1, ol, 0,0,0);
                ol = __builtin_amdgcn_mfma_f32_16x16x32_bf16(aol0[2], hb2, ol, 0,0,0);
                uint u0 = f2bf(sigmoidf(oh[0]+ol[0]+bo0[0]));
                uint u1 = f2bf(sigmoidf(oh[1]+ol[1]+bo0[1]));
                uint u2 = f2bf(sigmoidf(oh[2]+ol[2]+bo0[2]));
                uint u3 = f2bf(sigmoidf(oh[3]+ol[3]+bo0[3]));
                uint2 pk; pk.x = u0 | (u1<<16); pk.y = u2 | (u3<<16);
                *(uint2*)(obuf[nxt] + n*LSTR + 16*t0 + 4*g) = pk;
                if (w < 2){
                    floatx4 ph = {0.f,0.f,0.f,0.f}, pl = {0.f,0.f,0.f,0.f};
                    ph = __builtin_amdgcn_mfma_f32_16x16x32_bf16(aoh1[0], hb0, ph, 0,0,0);
                    ph = __builtin_amdgcn_mfma_f32_16x16x32_bf16(aoh1[1], hb1, ph, 0,0,0);
                    ph = __builtin_amdgcn_mfma_f32_16x16x32_bf16(aoh1[2], hb2, ph, 0,0,0);
                    pl = __builtin_amdgcn_mfma_f32_16x16x32_bf16(aol1[0], hb0, pl, 0,0,0);
                    pl = __builtin_amdgcn_mfma_f32_16x16x32_bf16(aol1[1], hb1, pl, 0,0,0);
                    pl = __builtin_amdgcn_mfma_f32_16x16x32_bf16(aol1[2], hb2, pl, 0,0,0);
                    uint v0 = f2bf(sigmoidf(ph[0]+pl[0]+bo1[0]));
                    uint v1 = f2bf(sigmoidf(ph[1]+pl[1]+bo1[1]));
                    uint v2 = f2bf(sigmoidf(ph[2]+pl[2]+bo1[2]));
                    uint v3 = f2bf(sigmoidf(ph[3]+pl[3]+bo1[3]));
                    uint2 qk; qk.x = v0 | (v1<<16); qk.y = v2 | (v3<<16);
                    *(uint2*)(obuf[nxt] + n*LSTR + 16*t1 + 4*g) = qk;
                }
            }
            xp_cur = xp_nxt; xp_nxt = xp_new;
            bar_lds();
        }
    } else {
        // ---- role B: z + out-phase. out-tiles: w3:{0..3} w4:{4..7} ----
        const int tb = 4*(w - 3);
        short8 af[4][3];
        float4 bf4[4];
        #pragma unroll
        for (int t = 0; t < 4; ++t){
            #pragma unroll
            for (int ks = 0; ks < 3; ++ks)
                af[t][ks] = *(const short8*)(wfh + (16*(tb+t) + n)*KP + ks*32 + g*8);
            bf4[t] = *(const float4*)(bfc + 16*(tb+t) + 4*g);
        }
        float* outbase = out + ((size_t)(b0 + n)*Sn)*Ln + 16*tb + 4*g;
        for (int i = 0; i < Sn+2; ++i){
            const int cur = i & 1, nxt = cur ^ 1;
            short8 hb0, hb1, hb2;
            if (i <= Sn){
                const ushort* hp = hbuf[cur] + n*LSTR + g*8;
                hb0 = *(const short8*)hp;
                hb1 = *(const short8*)(hp + 32);
                hb2 = *(const short8*)(hp + 64);
            }
            short8 ob0, ob1, ob2;
            if (i >= 2){
                const ushort* op = obuf[cur] + n*LSTR + g*8;
                ob0 = *(const short8*)op;
                ob1 = *(const short8*)(op + 32);
                ob2 = *(const short8*)(op + 64);
            }
            float4 xp_new = {0.f,0.f,0.f,0.f};
            if (i + 2 < Sn){
                int tok = sX[n*513 + i + 2];
                xp_new = *(const float4*)(embW + (size_t)tok*EW + j0);
            }
            if (i < Sn){ // z-phase -> h_i
                floatx4 zh = {0.f,0.f,0.f,0.f}, zl = {0.f,0.f,0.f,0.f};
                zh = __builtin_amdgcn_mfma_f32_16x16x32_bf16(a2h[0], hb0, zh, 0,0,0);
                zh = __builtin_amdgcn_mfma_f32_16x16x32_bf16(a2h[1], hb1, zh, 0,0,0);
                zh = __builtin_amdgcn_mfma_f32_16x16x32_bf16(a2h[2], hb2, zh, 0,0,0);
                zl = __builtin_amdgcn_mfma_f32_16x16x32_bf16(a2l[0], hb0, zl, 0,0,0);
                zl = __builtin_amdgcn_mfma_f32_16x16x32_bf16(a2l[1], hb1, zl, 0,0,0);
                zl = __builtin_amdgcn_mfma_f32_16x16x32_bf16(a2l[2], hb2, zl, 0,0,0);
                uint u0 = f2bf(sigmoidf(zh[0]+zl[0]+xp_cur.x));
                uint u1 = f2bf(sigmoidf(zh[1]+zl[1]+xp_cur.y));
                uint u2 = f2bf(sigmoidf(zh[2]+zl[2]+xp_cur.z));
                uint u3 = f2bf(sigmoidf(zh[3]+zl[3]+xp_cur.w));
                uint2 pk; pk.x = u0 | (u1<<16); pk.y = u2 | (u3<<16);
                *(uint2*)(hbuf[nxt] + n*LSTR + j0) = pk;
            }
            if (i >= 2){ // out-phase -> out_{i-2}
                float* orow = outbase + (size_t)(i-2)*Ln;
                #pragma unroll
                for (int t = 0; t < 4; ++t){
                    floatx4 ac = {0.f,0.f,0.f,0.f};
                    ac = __builtin_amdgcn_mfma_f32_16x16x32_bf16(af[t][0], ob0, ac, 0,0,0);
                    ac = __builtin_amdgcn_mfma_f32_16x16x32_bf16(af[t][1], ob1, ac, 0,0,0);
                    ac = __builtin_amdgcn_mfma_f32_16x16x32_bf16(af[t][2], ob2, ac, 0,0,0);
                    float4 res;
                    res.x = ac[0] + bf4[t].x; res.y = ac[1] + bf4[t].y;
                    res.z = ac[2] + bf4[t].z; res.w = ac[3] + bf4[t].w;
                    *(float4*)(orow + 16*t) = res;   // 4 consecutive l, 16B aligned
                }
            }
            xp_cur = xp_nxt; xp_nxt = xp_new;
            bar_lds();
        }
    }
}

extern "C" void kernel_launch(void* const* d_in, const int* in_sizes, int n_in,
                              void* d_out, int out_size, void* d_ws, size_t ws_size,
                              hipStream_t stream)
{
    const int*   X   = (const int*)d_in[0];
    const float* emb = (const float*)d_in[1];
    const float* W1  = (const float*)d_in[2];
    const float* b1  = (const float*)d_in[3];
    const float* W2  = (const float*)d_in[4];
    const float* b2  = (const float*)d_in[5];
    const float* Wo  = (const float*)d_in[6];
    const float* bo  = (const float*)d_in[7];
    const float* Wfc = (const float*)d_in[8];
    const float* bfc = (const float*)d_in[9];
    float* out = (float*)d_out;
    float* ws  = (float*)d_ws;

    float*  embW = ws + OFF_EMBW;
    ushort* w2h  = (ushort*)(ws + OFF_W2H);
    ushort* w2l  = (ushort*)(ws + OFF_W2L);
    ushort* woh  = (ushort*)(ws + OFF_WOH);
    ushort* wol  = (ushort*)(ws + OFF_WOL);
    ushort* wfh  = (ushort*)(ws + OFF_WFH);
    ushort* wfl  = (ushort*)(ws + OFF_WFL);

    k_wprep<<<dim3(48), dim3(256), 0, stream>>>(W2, Wo, Wfc, w2h, w2l, woh, wol, wfh, wfl);
    k_embproj<<<dim3(Vn/64), dim3(64), 0, stream>>>(emb, W1, b1, b2, embW);
    k_rnn_fused<<<dim3(Bn/16), dim3(320), 0, stream>>>(X, embW, w2h, w2l, woh, wol,
                                                       wfh, wfl, bo, bfc, out);
}

// Round 5
// 393.638 us; speedup vs baseline: 1.6698x; 1.6698x over previous
//
#include <hip/hip_runtime.h>
#include <hip/hip_bf16.h>

typedef unsigned int uint;
typedef unsigned short ushort;

constexpr int Bn = 256, Sn = 512, Vn = 32000, Dn = 100, Hn = 75, Ln = 128;
constexpr int EW = 80;    // embW row stride (floats), cols 75..79 zero
constexpr int KP = 96;    // h_all row stride (f16) = MFMA K-pad (3 x 32)
constexpr int W2S = 80;   // w2p row stride (f16)

// workspace layout (float units)
constexpr size_t OFF_EMBW = 0;                          // 32000*80   = 2,560,000 f
constexpr size_t OFF_HALL = OFF_EMBW + (size_t)Vn*EW;   // 131072*96 f16 = 6,291,456 f
constexpr size_t OFF_W2P  = OFF_HALL + (size_t)Bn*Sn*KP/2; // 80*80 f16 = 3200 f
constexpr size_t OFF_WOH  = OFF_W2P + 3200;             // 80*96 f16  = 3840 f
constexpr size_t OFF_WFH  = OFF_WOH + 3840;             // 128*96 f16 = 6144 f

typedef __attribute__((ext_vector_type(2))) _Float16 half2_t;
typedef __attribute__((ext_vector_type(8))) _Float16 half8;
typedef __attribute__((ext_vector_type(4))) float floatx4;

__device__ __forceinline__ ushort f2h(float f){
    union { _Float16 h; ushort u; } v; v.h = (_Float16)f; return v.u;
}
__device__ __forceinline__ half2_t as_h2(uint u){
    union { uint u; half2_t h; } v; v.u = u; return v.h;
}
__device__ __forceinline__ float sigmoidf(float z){ return 1.f/(1.f + __expf(-z)); }

// ---------------------------------------------------------------------------
// Prep: W2 -> [80][80] f16 (pad 0), Wo -> [80][96] f16, Wfc -> [128][96] f16,
// zero h_all pad cols 80..95 (so k_rnn never touches them).
// ---------------------------------------------------------------------------
__global__ __launch_bounds__(256) void k_wprep(
    const float* __restrict__ W2, const float* __restrict__ Wo,
    const float* __restrict__ Wfc, ushort* __restrict__ w2p,
    ushort* __restrict__ woh, ushort* __restrict__ wfh, ushort* __restrict__ h_all)
{
    const int tid = blockIdx.x*256 + threadIdx.x;
    const int stride = gridDim.x*256;
    for (int i = tid; i < 80*W2S; i += stride){
        int r = i / W2S, k = i % W2S;
        w2p[i] = (r < Hn && k < Hn) ? f2h(W2[r*Hn + k]) : (ushort)0;
    }
    for (int i = tid; i < 80*KP; i += stride){
        int r = i / KP, k = i % KP;
        woh[i] = (r < Hn && k < Hn) ? f2h(Wo[r*Hn + k]) : (ushort)0;
    }
    for (int i = tid; i < Ln*KP; i += stride){
        int l = i / KP, k = i % KP;
        wfh[i] = (k < Hn) ? f2h(Wfc[l*Hn + k]) : (ushort)0;
    }
    // h_all[row][80..95] = 0  (8 uints per row)
    uint* hu = (uint*)h_all;
    for (int i = tid; i < Bn*Sn*8; i += stride){
        int row = i >> 3, c = i & 7;
        hu[(size_t)row*48 + 40 + c] = 0u;
    }
}

// ---------------------------------------------------------------------------
// embW[v][j] = sum_d emb[v][d]*W1[j][d] + b1[j] + b2[j], stride EW=80,
// cols 75..79 zero. One wave per 64 vocab rows; W1 via wave-uniform s_loads.
// ---------------------------------------------------------------------------
__global__ __launch_bounds__(64) void k_embproj(
    const float* __restrict__ emb, const float* __restrict__ W1,
    const float* __restrict__ b1, const float* __restrict__ b2,
    float* __restrict__ embW)
{
    const int lane = threadIdx.x;
    const int v = blockIdx.x*64 + lane;
    const float4* ev = (const float4*)(emb + (size_t)v*Dn);
    float e[Dn];
    #pragma unroll
    for (int q = 0; q < Dn/4; ++q){
        float4 x = ev[q];
        e[4*q] = x.x; e[4*q+1] = x.y; e[4*q+2] = x.z; e[4*q+3] = x.w;
    }
    __shared__ float s_out[64*EW];
    #pragma unroll 4
    for (int j = 0; j < Hn; ++j){
        float a0 = b1[j] + b2[j], a1 = 0.f, a2 = 0.f, a3 = 0.f;
        const float* w = W1 + j*Dn;              // uniform -> s_loads
        #pragma unroll
        for (int d = 0; d < Dn; d += 4){
            a0 += w[d]*e[d];     a1 += w[d+1]*e[d+1];
            a2 += w[d+2]*e[d+2]; a3 += w[d+3]*e[d+3];
        }
        s_out[lane*EW + j] = (a0+a1) + (a2+a3);
    }
    #pragma unroll
    for (int j = Hn; j < EW; ++j) s_out[lane*EW + j] = 0.f;
    __syncthreads();
    float* dst = embW + (size_t)blockIdx.x*64*EW;
    for (int i = lane; i < 64*EW; i += 64) dst[i] = s_out[i];
}

// ---------------------------------------------------------------------------
// Sequential scan: ONE WAVE per batch row (256 blocks, 1/CU). Lane L computes
// h[L] and h[64+L]. h kept f16-packed in LDS: 10 ds_read_b128 broadcasts/step.
// Dot products: v_dot2_f32_f16, 8 independent acc chains. Zero barriers —
// intra-wave DS ordering is program order. embW gather prefetched 2 ahead.
// h written to h_all f16 (stride 96; cols 80..95 pre-zeroed by k_wprep).
// ---------------------------------------------------------------------------
__global__ __launch_bounds__(64) void k_rnn(
    const int* __restrict__ X, const float* __restrict__ embW,
    const ushort* __restrict__ w2p, ushort* __restrict__ h_all)
{
    const int b = blockIdx.x;
    const int L = threadIdx.x;
    __shared__ int sX[Sn];
    __shared__ __align__(16) ushort hl[80];
    for (int i = L; i < Sn; i += 64) sX[i] = X[b*Sn + i];
    if (L < 40) ((uint*)hl)[L] = 0u;          // h_{-1} = 0 (80 f16)
    // W2 rows L and 64+L (clamped; rows >=75 are zero) in registers, packed f16
    uint w1u[40], w2u[40];
    {
        const uint4* r1 = (const uint4*)(w2p + (size_t)L*W2S);
        int L2 = (64 + L < 80) ? (64 + L) : 79;
        const uint4* r2 = (const uint4*)(w2p + (size_t)L2*W2S);
        #pragma unroll
        for (int q = 0; q < 10; ++q){
            uint4 a = r1[q]; uint4 c = r2[q];
            w1u[4*q] = a.x; w1u[4*q+1] = a.y; w1u[4*q+2] = a.z; w1u[4*q+3] = a.w;
            w2u[4*q] = c.x; w2u[4*q+1] = c.y; w2u[4*q+2] = c.z; w2u[4*q+3] = c.w;
        }
    }
    __syncthreads();                           // single wave: trivial

    ushort* hout = h_all + (size_t)b*Sn*KP;
    // xp prefetch pipeline (2 deep): xp1 = embW[tok][L], xp2 = embW[tok][64+L]
    float x1c, x2c, x1n, x2n;
    {
        int t0 = sX[0], t1 = sX[1];
        x1c = embW[(size_t)t0*EW + L];
        x2c = (L < 16) ? embW[(size_t)t0*EW + 64 + L] : 0.f;
        x1n = embW[(size_t)t1*EW + L];
        x2n = (L < 16) ? embW[(size_t)t1*EW + 64 + L] : 0.f;
    }
    for (int s = 0; s < Sn; ++s){
        // read h (broadcast, conflict-free), 10x b128
        uint hv[40];
        #pragma unroll
        for (int q = 0; q < 10; ++q){
            uint4 x = *(const uint4*)(hl + q*8);
            hv[4*q] = x.x; hv[4*q+1] = x.y; hv[4*q+2] = x.z; hv[4*q+3] = x.w;
        }
        // issue next-next xp gather early (consumed at s+2)
        int tok = sX[(s+2 < Sn) ? s+2 : Sn-1];
        float x1f = embW[(size_t)tok*EW + L];
        float x2f = (L < 16) ? embW[(size_t)tok*EW + 64 + L] : 0.f;
        // dots: 8 independent chains
        float a0=0.f,a1=0.f,a2=0.f,a3=0.f, c0=0.f,c1=0.f,c2=0.f,c3=0.f;
        #pragma unroll
        for (int p = 0; p < 40; p += 4){
            a0 = __builtin_amdgcn_fdot2(as_h2(w1u[p]),   as_h2(hv[p]),   a0, false);
            a1 = __builtin_amdgcn_fdot2(as_h2(w1u[p+1]), as_h2(hv[p+1]), a1, false);
            a2 = __builtin_amdgcn_fdot2(as_h2(w1u[p+2]), as_h2(hv[p+2]), a2, false);
            a3 = __builtin_amdgcn_fdot2(as_h2(w1u[p+3]), as_h2(hv[p+3]), a3, false);
            c0 = __builtin_amdgcn_fdot2(as_h2(w2u[p]),   as_h2(hv[p]),   c0, false);
            c1 = __builtin_amdgcn_fdot2(as_h2(w2u[p+1]), as_h2(hv[p+1]), c1, false);
            c2 = __builtin_amdgcn_fdot2(as_h2(w2u[p+2]), as_h2(hv[p+2]), c2, false);
            c3 = __builtin_amdgcn_fdot2(as_h2(w2u[p+3]), as_h2(hv[p+3]), c3, false);
        }
        float h1 = sigmoidf(((a0+a1)+(a2+a3)) + x1c);
        float h2 = sigmoidf(((c0+c1)+(c2+c3)) + x2c);
        if (L >= 11) h2 = 0.f;                 // j = 75..79 pad and beyond
        ushort u1 = f2h(h1);
        hl[L] = u1;
        hout[(size_t)s*KP + L] = u1;
        if (L < 16){
            ushort u2 = f2h(h2);
            hl[64 + L] = u2;                   // keeps hl[75..79] = 0
            hout[(size_t)s*KP + 64 + L] = u2;
        }
        x1c = x1n; x2c = x2n; x1n = x1f; x2n = x2f;
        // no barrier: single-wave DS ordering guarantees visibility
    }
}

// ---------------------------------------------------------------------------
// Epilogue GEMM via MFMA 16x16x32 f16. Per block: 4 waves x 16 rows.
// Phase1: Z = H(16x96)@Wo^T + bo -> sigmoid -> O f16 in LDS (stride 104);
// Phase2: OUT = O@Wfc^T + bfc.
// C/D frag: col=lane&15, row=(lane>>4)*4+reg (m89-verified, dtype-indep).
// ---------------------------------------------------------------------------
__global__ __launch_bounds__(256) void k_out(
    const ushort* __restrict__ h_all, const ushort* __restrict__ woh,
    const ushort* __restrict__ wfh, const float* __restrict__ bo,
    const float* __restrict__ bfc, float* __restrict__ out)
{
    const int lane = threadIdx.x & 63;
    const int w    = threadIdx.x >> 6;
    const size_t r0 = (size_t)blockIdx.x*64 + w*16;
    const int m = lane & 15;
    const int g = lane >> 4;
    __shared__ __align__(16) ushort o_lds[4][16*104];
    ushort* ot = o_lds[w];
    // zero O pad cols 80..95 (read by k-step 2); wave-local, no barrier needed
    for (int i = lane; i < 128; i += 64){
        int row = i >> 3, cw = i & 7;
        *(uint*)&ot[row*104 + 80 + cw*2] = 0u;
    }
    // ---- Phase 1: Z = H @ Wo^T ----
    floatx4 acc1[5] = {};
    const ushort* hbase = h_all + r0*KP;
    #pragma unroll
    for (int ks = 0; ks < 3; ++ks){
        half8 a = *(const half8*)(hbase + (size_t)m*KP + ks*32 + g*8);
        #pragma unroll
        for (int t = 0; t < 5; ++t){
            half8 bt = *(const half8*)(woh + (16*t + m)*KP + ks*32 + g*8);
            acc1[t] = __builtin_amdgcn_mfma_f32_16x16x32_f16(a, bt, acc1[t], 0, 0, 0);
        }
    }
    // ---- bo + sigmoid -> O (f16, C layout) ----
    #pragma unroll
    for (int t = 0; t < 5; ++t){
        int n = 16*t + m;
        float bias = (n < Hn) ? bo[n] : 0.f;
        #pragma unroll
        for (int r = 0; r < 4; ++r){
            int row = g*4 + r;
            float o = sigmoidf(acc1[t][r] + bias);
            if (n >= Hn) o = 0.f;              // pad rows -> z=0 -> 0.5; kill
            ot[row*104 + n] = f2h(o);
        }
    }
    // wave-local LDS RAW: in-order DS pipe within a wave; no barrier
    // ---- Phase 2: OUT = O @ Wfc^T ----
    floatx4 acc2[8] = {};
    #pragma unroll
    for (int ks = 0; ks < 3; ++ks){
        half8 a = *(const half8*)(ot + m*104 + ks*32 + g*8);
        #pragma unroll
        for (int t = 0; t < 8; ++t){
            half8 bt = *(const half8*)(wfh + (16*t + m)*KP + ks*32 + g*8);
            acc2[t] = __builtin_amdgcn_mfma_f32_16x16x32_f16(a, bt, acc2[t], 0, 0, 0);
        }
    }
    // ---- bfc + store ----
    float* orow = out + r0*Ln;
    #pragma unroll
    for (int t = 0; t < 8; ++t){
        float bias = bfc[16*t + m];
        #pragma unroll
        for (int r = 0; r < 4; ++r){
            int row = g*4 + r;
            orow[(size_t)row*Ln + 16*t + m] = acc2[t][r] + bias;
        }
    }
}

extern "C" void kernel_launch(void* const* d_in, const int* in_sizes, int n_in,
                              void* d_out, int out_size, void* d_ws, size_t ws_size,
                              hipStream_t stream)
{
    const int*   X   = (const int*)d_in[0];
    const float* emb = (const float*)d_in[1];
    const float* W1  = (const float*)d_in[2];
    const float* b1  = (const float*)d_in[3];
    const float* W2  = (const float*)d_in[4];
    const float* b2  = (const float*)d_in[5];
    const float* Wo  = (const float*)d_in[6];
    const float* bo  = (const float*)d_in[7];
    const float* Wfc = (const float*)d_in[8];
    const float* bfc = (const float*)d_in[9];
    float* out = (float*)d_out;
    float* ws  = (float*)d_ws;

    float*  embW = ws + OFF_EMBW;
    ushort* hall = (ushort*)(ws + OFF_HALL);
    ushort* w2p  = (ushort*)(ws + OFF_W2P);
    ushort* woh  = (ushort*)(ws + OFF_WOH);
    ushort* wfh  = (ushort*)(ws + OFF_WFH);

    k_wprep<<<dim3(512), dim3(256), 0, stream>>>(W2, Wo, Wfc, w2p, woh, wfh, hall);
    k_embproj<<<dim3(Vn/64), dim3(64), 0, stream>>>(emb, W1, b1, b2, embW);
    k_rnn<<<dim3(Bn), dim3(64), 0, stream>>>(X, embW, w2p, hall);
    k_out<<<dim3((Bn*Sn)/64), dim3(256), 0, stream>>>(hall, woh, wfh, bo, bfc, out);
}